// Round 4
// baseline (1578.753 us; speedup 1.0000x reference)
//
#include <hip/hip_runtime.h>
#include <math.h>

#define N0   17186
#define FIN  6
#define H1C  64
#define H2C  32
#define KSEL 12031
#define BATCH 64
#define NE   500000
#define NT   (BATCH * N0)

typedef unsigned int uint;
typedef unsigned char uchar;

__device__ __forceinline__ uint keyOf(float f) {
    uint u = __float_as_uint(f);
    return (u & 0x80000000u) ? ~u : (u | 0x80000000u);
}

// ---------- edge dtype detection / normalization ----------
__global__ void k_detect(const uint* ei, int* flag64) {
    __shared__ int any;
    if (threadIdx.x == 0) any = 0;
    __syncthreads();
    for (int i = threadIdx.x; i < 1024; i += blockDim.x)
        if (ei[2 * i + 1] != 0u) any = 1;
    __syncthreads();
    if (threadIdx.x == 0) *flag64 = any ? 0 : 1;
}

__global__ void k_convert(const void* ei, const int* flag64, int* src, int* dst) {
    int f = *flag64;
    int stride = gridDim.x * blockDim.x;
    for (int i = blockIdx.x * blockDim.x + threadIdx.x; i < 2 * NE; i += stride) {
        int v = f ? (int)((const long long*)ei)[i] : ((const int*)ei)[i];
        if (i < NE) src[i] = v; else dst[i - NE] = v;
    }
}

// ---------- CSR build ----------
__global__ void k_deg(const int* dst, uint* deg) {
    int e = blockIdx.x * blockDim.x + threadIdx.x;
    if (e < NE) atomicAdd(&deg[dst[e]], 1u);
}

__global__ void k_scan(const uint* deg, int* rowptr) {
    __shared__ uint tsum[256];
    int tid = threadIdx.x;
    const int CH = (N0 + 255) / 256;  // 68
    int beg = tid * CH, end = beg + CH;
    if (end > N0) end = N0;
    uint s = 0;
    for (int i = beg; i < end; i++) s += deg[i];
    tsum[tid] = s;
    __syncthreads();
    for (int off = 1; off < 256; off <<= 1) {
        uint v = tsum[tid];
        uint a = (tid >= off) ? tsum[tid - off] : 0u;
        __syncthreads();
        tsum[tid] = v + a;
        __syncthreads();
    }
    uint run = (tid > 0) ? tsum[tid - 1] : 0u;
    for (int i = beg; i < end; i++) { rowptr[i] = (int)run; run += deg[i]; }
    if (tid == 255) rowptr[N0] = (int)run;
}

__global__ void k_scatter(const int* src, const int* dst, const int* rowptr,
                          uint* cnt, int* csr) {
    int e = blockIdx.x * blockDim.x + threadIdx.x;
    if (e < NE) {
        int d = dst[e];
        uint p = atomicAdd(&cnt[d], 1u);
        csr[rowptr[d] + (int)p] = src[e];
    }
}

// ---------- conv1 (graph 0) ----------
__global__ void k_xw1(const float* x, const float* W1, float* xw1) {
    int t = blockIdx.x * blockDim.x + threadIdx.x;
    if (t >= N0 * H1C) return;
    int i = t >> 6, h = t & 63;
    float acc = 0.f;
#pragma unroll
    for (int f = 0; f < FIN; f++) acc += x[i * FIN + f] * W1[f * H1C + h];
    xw1[t] = acc;
}

__global__ void k_dinv(const uint* deg, float* dinv) {
    int i = blockIdx.x * blockDim.x + threadIdx.x;
    if (i < N0) dinv[i] = rsqrtf(1.0f + (float)deg[i]);
}

// gather conv1 messages + finish h1 (fused fin1), 4-way unrolled
__global__ void k_gath1(const int* rowptr, const int* csr, const float* dinv,
                        const float* xw1, const float* b1, float* h1) {
    int wid = (blockIdx.x * blockDim.x + threadIdx.x) >> 6;
    int lane = threadIdx.x & 63;
    if (wid >= N0) return;
    int d = wid;
    int beg = rowptr[d], end = rowptr[d + 1];
    float a0 = 0.f, a1 = 0.f, a2 = 0.f, a3 = 0.f;
    int e = beg;
    for (; e + 4 <= end; e += 4) {
        int s0 = csr[e], s1 = csr[e + 1], s2 = csr[e + 2], s3 = csr[e + 3];
        a0 += xw1[(size_t)s0 * H1C + lane] * dinv[s0];
        a1 += xw1[(size_t)s1 * H1C + lane] * dinv[s1];
        a2 += xw1[(size_t)s2 * H1C + lane] * dinv[s2];
        a3 += xw1[(size_t)s3 * H1C + lane] * dinv[s3];
    }
    for (; e < end; e++) {
        int s = csr[e];
        a0 += xw1[(size_t)s * H1C + lane] * dinv[s];
    }
    float acc = (a0 + a1) + (a2 + a3);
    float did = dinv[d];
    float v = acc * did + xw1[(size_t)d * H1C + lane] * did * did + b1[lane];
    h1[(size_t)d * H1C + lane] = fmaxf(v, 0.f);
}

// ---------- pooling score ----------
__global__ void k_h1w(const float* h1, const float* Wp, float* h1w) {
    int i = blockIdx.x * blockDim.x + threadIdx.x;
    if (i >= N0) return;
    const float* row = h1 + (size_t)i * H1C;
    float acc = 0.f;
#pragma unroll
    for (int h = 0; h < H1C; h++) acc += row[h] * Wp[h];
    h1w[i] = acc;
}

// graph-0 score: gather + self-loop (fused smsg+score0)
__global__ void k_gscore0(const int* rowptr, const int* csr, const float* dinv,
                          const float* h1w, const float* bp, float* score) {
    int d = blockIdx.x * blockDim.x + threadIdx.x;
    if (d >= N0) return;
    float acc = 0.f;
    int beg = rowptr[d], end = rowptr[d + 1];
    for (int e = beg; e < end; e++) {
        int s = csr[e];
        acc += h1w[s] * dinv[s];
    }
    float did = dinv[d];
    score[d] = acc * did + h1w[d] * did * did + bp[0];
}

// graphs 1..63: score = relu(x@W1+b1) . Wp + bp  (thread per node)
__global__ void k_score_rest(const float* x, const float* W1, const float* b1,
                             const float* Wp, const float* bp, float* score) {
    int idx = blockIdx.x * blockDim.x + threadIdx.x;
    int n = N0 + idx;
    if (n >= NT) return;
    float xr[FIN];
#pragma unroll
    for (int f = 0; f < FIN; f++) xr[f] = x[(size_t)n * FIN + f];
    float sc = bp[0];
#pragma unroll
    for (int h = 0; h < H1C; h++) {
        float a = b1[h];
#pragma unroll
        for (int f = 0; f < FIN; f++) a += xr[f] * W1[f * H1C + h];
        sc += fmaxf(a, 0.f) * Wp[h];
    }
    score[n] = sc;
}

// ---------- per-graph top-K selection (radix select on float keys) ----------
__global__ void k_topk(const float* score, uchar* sel) {
    int g = blockIdx.x;
    const float* sc = score + (size_t)g * N0;
    uchar* sl = sel + (size_t)g * N0;
    __shared__ uint hist[4][256];
    __shared__ uint shPrefix, shWant;
    __shared__ uint wtot[4];
    int tid = threadIdx.x;
    int wave = tid >> 6, lane = tid & 63;
    uint prefix = 0, want = KSEL;
    for (int pass = 0; pass < 4; pass++) {
        int shift = 24 - 8 * pass;
#pragma unroll
        for (int w = 0; w < 4; w++) hist[w][tid] = 0;
        __syncthreads();
        for (int i = tid; i < N0; i += 256) {
            uint k = keyOf(sc[i]);
            bool active = (pass == 0) || ((k >> (shift + 8)) == prefix);
            if (active) atomicAdd(&hist[wave][(k >> shift) & 255], 1u);
        }
        __syncthreads();
        uint merged = hist[0][tid] + hist[1][tid] + hist[2][tid] + hist[3][tid];
        hist[0][tid] = merged;
        __syncthreads();
        if (tid == 0) {
            uint cum = 0; int d = 255;
            for (; d > 0; d--) { cum += hist[0][d]; if (cum >= want) break; }
            if (cum < want) cum += hist[0][0];        // d==0 fallthrough
            shWant = want - (cum - hist[0][d]);
            shPrefix = (prefix << 8) | (uint)d;
        }
        __syncthreads();
        prefix = shPrefix; want = shWant;
        __syncthreads();
    }
    uint T = prefix, needEq = want;
    uint runningEq = 0;
    for (int base = 0; base < N0; base += 256) {
        int i = base + tid;
        uint k = (i < N0) ? keyOf(sc[i]) : 0u;
        bool isEq = (i < N0) && (k == T);
        unsigned long long mask = __ballot(isEq);
        uint wprefix = (uint)__popcll(mask & ((1ull << lane) - 1ull));
        uint wcount = (uint)__popcll(mask);
        if (lane == 0) wtot[wave] = wcount;
        __syncthreads();
        uint before = 0;
#pragma unroll
        for (int w = 0; w < 4; w++) if (w < wave) before += wtot[w];
        uint total = wtot[0] + wtot[1] + wtot[2] + wtot[3];
        if (i < N0) {
            uchar s = 0;
            if (k > T) s = 1;
            else if (isEq && (runningEq + before + wprefix) < needEq) s = 1;
            sl[i] = s;
        }
        runningEq += total;
        __syncthreads();
    }
}

// ---------- conv2 (graph 0, selection-filtered) ----------
// dinv2[d] = sel[d] ? rsqrt(1 + #selected in-edges) : 0   (0 acts as edge mask)
__global__ void k_gdinv2(const int* rowptr, const int* csr, const uchar* sel,
                         float* dinv2) {
    int d = blockIdx.x * blockDim.x + threadIdx.x;
    if (d >= N0) return;
    float r = 0.f;
    if (sel[d]) {
        int c = 0;
        int beg = rowptr[d], end = rowptr[d + 1];
        for (int e = beg; e < end; e++) c += sel[csr[e]];
        r = rsqrtf(1.f + (float)c);
    }
    dinv2[d] = r;
}

__global__ void k_xw2(const float* h1, const float* score, const uchar* sel,
                      const float* W2, float* xw2) {
    int gt = blockIdx.x * blockDim.x + threadIdx.x;
    int i = gt >> 5, c = gt & 31;
    if (i >= N0) return;
    if (!sel[i]) return;
    float t = tanhf(score[i]);
    const float* row = h1 + (size_t)i * H1C;
    float acc = 0.f;
#pragma unroll
    for (int h = 0; h < H1C; h++) acc += row[h] * W2[h * H2C + c];
    xw2[i * H2C + c] = acc * t;
}

__global__ void k_gath2(const int* rowptr, const int* csr, const uchar* sel,
                        const float* dinv2, const float* xw2, float* acc2) {
    int wid = (blockIdx.x * blockDim.x + threadIdx.x) >> 6;
    int lane = threadIdx.x & 63;
    if (wid >= N0) return;
    int d = wid;
    if (!sel[d]) return;
    int c = lane & 31;
    int beg = rowptr[d], end = rowptr[d + 1];
    float a0 = 0.f, a1 = 0.f;
    int e = beg + (lane >> 5);
    for (; e + 2 < end; e += 4) {   // this half-wave handles e, e+2
        int s0 = csr[e], s1 = csr[e + 2];
        a0 += xw2[(size_t)s0 * H2C + c] * dinv2[s0];
        a1 += xw2[(size_t)s1 * H2C + c] * dinv2[s1];
    }
    if (e < end) {
        int s = csr[e];
        a0 += xw2[(size_t)s * H2C + c] * dinv2[s];
    }
    float acc = a0 + a1;
    acc += __shfl_xor(acc, 32, 64);
    if (lane < 32) acc2[(size_t)d * H2C + c] = acc * dinv2[d];
}

__global__ void k_fin2(const float* acc2, const float* xw2, const float* dinv2,
                       const uchar* sel, const float* b2, float* gmax) {
    __shared__ float m[32];
    int tid = threadIdx.x;
    if (tid < 32) m[tid] = 0.f;
    __syncthreads();
    int i = blockIdx.x * 8 + (tid >> 5);
    int c = tid & 31;
    float v = 0.f;
    if (i < N0 && sel[i]) {
        float di = dinv2[i];
        v = fmaxf(acc2[(size_t)i * H2C + c] + xw2[(size_t)i * H2C + c] * di * di + b2[c], 0.f);
    }
    atomicMax((int*)&m[c], __float_as_int(v));
    __syncthreads();
    if (tid < 32) atomicMax((int*)&gmax[tid], __float_as_int(m[tid]));
}

// ---------- graphs 1..63: h2 + max pool ----------
// 68 blocks per graph (4 waves each = 272 waves >= ceil(17186/64)=269).
// __launch_bounds__(256,4): VGPR cap 128 so acc[32]+xr[6] stay in registers
// (R2/R3 regression root cause: default cap ~56 VGPR -> scratch spill,
//  WRITE_SIZE 93MB of spill leakage).
#define BPGR 68
__global__ __launch_bounds__(256, 4)
void k_rest_pool(const float* x, const float* score, const uchar* sel,
                 const float* W1, const float* b1,
                 const float* W2, const float* b2, float* gmax) {
    __shared__ float m[H2C];
    int tid = threadIdx.x;
    if (tid < H2C) m[tid] = 0.f;
    __syncthreads();
    int lane = tid & 63;
    int g = blockIdx.x / BPGR + 1;
    int wslot = (blockIdx.x % BPGR) * 4 + (tid >> 6);
    int li = wslot * 64 + lane;
    bool inb = li < N0;
    int n = inb ? (g * N0 + li) : 0;
    bool valid = inb && sel[n];
    float xr[FIN];
#pragma unroll
    for (int f = 0; f < FIN; f++) xr[f] = 0.f;
    if (valid) {
        const float* xp = x + (size_t)n * FIN;
#pragma unroll
        for (int f = 0; f < FIN; f++) xr[f] = xp[f];
    }
    float t = valid ? tanhf(score[n]) : 0.f;
    float acc[H2C];
#pragma unroll
    for (int c = 0; c < H2C; c++) acc[c] = 0.f;
#pragma unroll
    for (int h = 0; h < H1C; h++) {
        float a = b1[h];
#pragma unroll
        for (int f = 0; f < FIN; f++) a += xr[f] * W1[f * H1C + h];
        float hv = fmaxf(a, 0.f);
#pragma unroll
        for (int c = 0; c < H2C; c++) acc[c] += hv * W2[h * H2C + c];
    }
#pragma unroll
    for (int c = 0; c < H2C; c++) {
        float v = valid ? fmaxf(t * acc[c] + b2[c], 0.f) : 0.f;
#pragma unroll
        for (int o = 32; o > 0; o >>= 1) v = fmaxf(v, __shfl_xor(v, o, 64));
        if (lane == 0) atomicMax((int*)&m[c], __float_as_int(v));
    }
    __syncthreads();
    if (tid < H2C) atomicMax((int*)&gmax[g * H2C + tid], __float_as_int(m[tid]));
}

// ---------- readout ----------
__global__ void k_final(const float* gmax, const float* Wf, const float* bf, float* out) {
    int g = threadIdx.x;
    if (g < BATCH) {
        float acc = bf[0];
        for (int c = 0; c < H2C; c++) acc += gmax[g * H2C + c] * Wf[c];
        out[g] = 1.f / (1.f + expf(-acc));
    }
}

extern "C" void kernel_launch(void* const* d_in, const int* in_sizes, int n_in,
                              void* d_out, int out_size, void* d_ws, size_t ws_size,
                              hipStream_t stream) {
    const float* data = (const float*)d_in[0];
    const void*  ei   = d_in[1];
    const float* W1   = (const float*)d_in[2];
    const float* b1   = (const float*)d_in[3];
    const float* Wp   = (const float*)d_in[4];
    const float* bp   = (const float*)d_in[5];
    const float* W2   = (const float*)d_in[6];
    const float* b2   = (const float*)d_in[7];
    const float* Wf   = (const float*)d_in[8];
    const float* bf   = (const float*)d_in[9];
    float* out = (float*)d_out;

    char* ws = (char*)d_ws;
    size_t off = 0;
    auto A = [&](size_t bytes) -> size_t {
        size_t o = off; off += (bytes + 511) & ~(size_t)511; return o;
    };
    // zero-initialized region (single memset)
    size_t o_deg0 = A((size_t)N0 * 4);
    size_t o_cnt  = A((size_t)N0 * 4);
    size_t o_gmax = A((size_t)BATCH * H2C * 4);
    size_t zbytes = off;
    // rest
    size_t o_src  = A((size_t)NE * 4);
    size_t o_dst  = A((size_t)NE * 4);
    size_t o_rp   = A((size_t)(N0 + 1) * 4);
    size_t o_csr  = A((size_t)NE * 4);
    size_t o_xw1  = A((size_t)N0 * H1C * 4);
    size_t o_h1   = A((size_t)N0 * H1C * 4);
    size_t o_di0  = A((size_t)N0 * 4);
    size_t o_di2  = A((size_t)N0 * 4);
    size_t o_h1w  = A((size_t)N0 * 4);
    size_t o_scr  = A((size_t)NT * 4);
    size_t o_sel  = A((size_t)NT);
    size_t o_xw2  = A((size_t)N0 * H2C * 4);
    size_t o_acc2 = A((size_t)N0 * H2C * 4);
    size_t o_flag = A(4);

    uint*  deg0 = (uint*)(ws + o_deg0);
    uint*  cnt  = (uint*)(ws + o_cnt);
    float* gmax = (float*)(ws + o_gmax);
    int*   src  = (int*)(ws + o_src);
    int*   dst  = (int*)(ws + o_dst);
    int*   rp   = (int*)(ws + o_rp);
    int*   csr  = (int*)(ws + o_csr);
    float* xw1  = (float*)(ws + o_xw1);
    float* h1   = (float*)(ws + o_h1);
    float* di0  = (float*)(ws + o_di0);
    float* di2  = (float*)(ws + o_di2);
    float* h1w  = (float*)(ws + o_h1w);
    float* scr  = (float*)(ws + o_scr);
    uchar* sel  = (uchar*)(ws + o_sel);
    float* xw2  = (float*)(ws + o_xw2);
    float* acc2 = (float*)(ws + o_acc2);
    int*   flag = (int*)(ws + o_flag);

    hipMemsetAsync(ws, 0, zbytes, stream);

    k_detect<<<1, 256, 0, stream>>>((const uint*)ei, flag);
    k_convert<<<2048, 256, 0, stream>>>(ei, flag, src, dst);
    k_deg<<<(NE + 255) / 256, 256, 0, stream>>>(dst, deg0);
    k_scan<<<1, 256, 0, stream>>>(deg0, rp);
    k_scatter<<<(NE + 255) / 256, 256, 0, stream>>>(src, dst, rp, cnt, csr);
    k_xw1<<<(N0 * H1C + 255) / 256, 256, 0, stream>>>(data, W1, xw1);
    k_dinv<<<(N0 + 255) / 256, 256, 0, stream>>>(deg0, di0);
    k_gath1<<<(N0 * 64 + 255) / 256, 256, 0, stream>>>(rp, csr, di0, xw1, b1, h1);
    k_h1w<<<(N0 + 255) / 256, 256, 0, stream>>>(h1, Wp, h1w);
    k_gscore0<<<(N0 + 255) / 256, 256, 0, stream>>>(rp, csr, di0, h1w, bp, scr);
    k_score_rest<<<(NT - N0 + 255) / 256, 256, 0, stream>>>(data, W1, b1, Wp, bp, scr);
    k_topk<<<BATCH, 256, 0, stream>>>(scr, sel);
    k_gdinv2<<<(N0 + 255) / 256, 256, 0, stream>>>(rp, csr, sel, di2);
    k_xw2<<<(N0 * H2C + 255) / 256, 256, 0, stream>>>(h1, scr, sel, W2, xw2);
    k_gath2<<<(N0 * 64 + 255) / 256, 256, 0, stream>>>(rp, csr, sel, di2, xw2, acc2);
    k_fin2<<<(N0 + 7) / 8, 256, 0, stream>>>(acc2, xw2, di2, sel, b2, gmax);
    k_rest_pool<<<(BATCH - 1) * BPGR, 256, 0, stream>>>(data, scr, sel, W1, b1, W2, b2, gmax);
    k_final<<<1, 64, 0, stream>>>(gmax, Wf, bf, out);
}

// Round 6
// 846.605 us; speedup vs baseline: 1.8648x; 1.8648x over previous
//
#include <hip/hip_runtime.h>
#include <math.h>

#define N0   17186
#define FIN  6
#define H1C  64
#define H2C  32
#define KSEL 12031
#define BATCH 64
#define NE   500000
#define NT   (BATCH * N0)

typedef unsigned int uint;
typedef unsigned char uchar;

__device__ __forceinline__ uint keyOf(float f) {
    uint u = __float_as_uint(f);
    return (u & 0x80000000u) ? ~u : (u | 0x80000000u);
}

// ---------- edge dtype detection / normalization ----------
__global__ void k_detect(const uint* ei, int* flag64) {
    __shared__ int any;
    if (threadIdx.x == 0) any = 0;
    __syncthreads();
    for (int i = threadIdx.x; i < 1024; i += blockDim.x)
        if (ei[2 * i + 1] != 0u) any = 1;
    __syncthreads();
    if (threadIdx.x == 0) *flag64 = any ? 0 : 1;
}

__global__ void k_convert(const void* ei, const int* flag64, int* src, int* dst) {
    int f = *flag64;
    int stride = gridDim.x * blockDim.x;
    for (int i = blockIdx.x * blockDim.x + threadIdx.x; i < 2 * NE; i += stride) {
        int v = f ? (int)((const long long*)ei)[i] : ((const int*)ei)[i];
        if (i < NE) src[i] = v; else dst[i - NE] = v;
    }
}

// ---------- CSR build ----------
__global__ void k_deg(const int* dst, uint* deg) {
    int e = blockIdx.x * blockDim.x + threadIdx.x;
    if (e < NE) atomicAdd(&deg[dst[e]], 1u);
}

__global__ void k_scan(const uint* deg, int* rowptr) {
    __shared__ uint tsum[256];
    int tid = threadIdx.x;
    const int CH = (N0 + 255) / 256;  // 68
    int beg = tid * CH, end = beg + CH;
    if (end > N0) end = N0;
    uint s = 0;
    for (int i = beg; i < end; i++) s += deg[i];
    tsum[tid] = s;
    __syncthreads();
    for (int off = 1; off < 256; off <<= 1) {
        uint v = tsum[tid];
        uint a = (tid >= off) ? tsum[tid - off] : 0u;
        __syncthreads();
        tsum[tid] = v + a;
        __syncthreads();
    }
    uint run = (tid > 0) ? tsum[tid - 1] : 0u;
    for (int i = beg; i < end; i++) { rowptr[i] = (int)run; run += deg[i]; }
    if (tid == 255) rowptr[N0] = (int)run;
}

__global__ void k_scatter(const int* src, const int* dst, const int* rowptr,
                          uint* cnt, int* csr) {
    int e = blockIdx.x * blockDim.x + threadIdx.x;
    if (e < NE) {
        int d = dst[e];
        uint p = atomicAdd(&cnt[d], 1u);
        csr[rowptr[d] + (int)p] = src[e];
    }
}

// ---------- conv1 (graph 0) ----------
__global__ void k_xw1(const float* x, const float* W1, float* xw1) {
    int t = blockIdx.x * blockDim.x + threadIdx.x;
    if (t >= N0 * H1C) return;
    int i = t >> 6, h = t & 63;
    float acc = 0.f;
#pragma unroll
    for (int f = 0; f < FIN; f++) acc += x[i * FIN + f] * W1[f * H1C + h];
    xw1[t] = acc;
}

__global__ void k_dinv(const uint* deg, float* dinv) {
    int i = blockIdx.x * blockDim.x + threadIdx.x;
    if (i < N0) dinv[i] = rsqrtf(1.0f + (float)deg[i]);
}

// gather conv1 messages + finish h1 (fused fin1), 4-way unrolled
__global__ void k_gath1(const int* rowptr, const int* csr, const float* dinv,
                        const float* xw1, const float* b1, float* h1) {
    int wid = (blockIdx.x * blockDim.x + threadIdx.x) >> 6;
    int lane = threadIdx.x & 63;
    if (wid >= N0) return;
    int d = wid;
    int beg = rowptr[d], end = rowptr[d + 1];
    float a0 = 0.f, a1 = 0.f, a2 = 0.f, a3 = 0.f;
    int e = beg;
    for (; e + 4 <= end; e += 4) {
        int s0 = csr[e], s1 = csr[e + 1], s2 = csr[e + 2], s3 = csr[e + 3];
        a0 += xw1[(size_t)s0 * H1C + lane] * dinv[s0];
        a1 += xw1[(size_t)s1 * H1C + lane] * dinv[s1];
        a2 += xw1[(size_t)s2 * H1C + lane] * dinv[s2];
        a3 += xw1[(size_t)s3 * H1C + lane] * dinv[s3];
    }
    for (; e < end; e++) {
        int s = csr[e];
        a0 += xw1[(size_t)s * H1C + lane] * dinv[s];
    }
    float acc = (a0 + a1) + (a2 + a3);
    float did = dinv[d];
    float v = acc * did + xw1[(size_t)d * H1C + lane] * did * did + b1[lane];
    h1[(size_t)d * H1C + lane] = fmaxf(v, 0.f);
}

// ---------- pooling score ----------
__global__ void k_h1w(const float* h1, const float* Wp, float* h1w) {
    int i = blockIdx.x * blockDim.x + threadIdx.x;
    if (i >= N0) return;
    const float* row = h1 + (size_t)i * H1C;
    float acc = 0.f;
#pragma unroll
    for (int h = 0; h < H1C; h++) acc += row[h] * Wp[h];
    h1w[i] = acc;
}

// graph-0 score: gather + self-loop (fused smsg+score0)
__global__ void k_gscore0(const int* rowptr, const int* csr, const float* dinv,
                          const float* h1w, const float* bp, float* score) {
    int d = blockIdx.x * blockDim.x + threadIdx.x;
    if (d >= N0) return;
    float acc = 0.f;
    int beg = rowptr[d], end = rowptr[d + 1];
    for (int e = beg; e < end; e++) {
        int s = csr[e];
        acc += h1w[s] * dinv[s];
    }
    float did = dinv[d];
    score[d] = acc * did + h1w[d] * did * did + bp[0];
}

// graphs 1..63: score = relu(x@W1+b1) . Wp + bp  (thread per node)
__global__ void k_score_rest(const float* x, const float* W1, const float* b1,
                             const float* Wp, const float* bp, float* score) {
    int idx = blockIdx.x * blockDim.x + threadIdx.x;
    int n = N0 + idx;
    if (n >= NT) return;
    float xr[FIN];
#pragma unroll
    for (int f = 0; f < FIN; f++) xr[f] = x[(size_t)n * FIN + f];
    float sc = bp[0];
#pragma unroll
    for (int h = 0; h < H1C; h++) {
        float a = b1[h];
#pragma unroll
        for (int f = 0; f < FIN; f++) a += xr[f] * W1[f * H1C + h];
        sc += fmaxf(a, 0.f) * Wp[h];
    }
    score[n] = sc;
}

// ---------- per-graph top-K selection (radix select on float keys) ----------
__global__ void k_topk(const float* score, uchar* sel) {
    int g = blockIdx.x;
    const float* sc = score + (size_t)g * N0;
    uchar* sl = sel + (size_t)g * N0;
    __shared__ uint hist[4][256];
    __shared__ uint shPrefix, shWant;
    __shared__ uint wtot[4];
    int tid = threadIdx.x;
    int wave = tid >> 6, lane = tid & 63;
    uint prefix = 0, want = KSEL;
    for (int pass = 0; pass < 4; pass++) {
        int shift = 24 - 8 * pass;
#pragma unroll
        for (int w = 0; w < 4; w++) hist[w][tid] = 0;
        __syncthreads();
        for (int i = tid; i < N0; i += 256) {
            uint k = keyOf(sc[i]);
            bool active = (pass == 0) || ((k >> (shift + 8)) == prefix);
            if (active) atomicAdd(&hist[wave][(k >> shift) & 255], 1u);
        }
        __syncthreads();
        uint merged = hist[0][tid] + hist[1][tid] + hist[2][tid] + hist[3][tid];
        hist[0][tid] = merged;
        __syncthreads();
        if (tid == 0) {
            uint cum = 0; int d = 255;
            for (; d > 0; d--) { cum += hist[0][d]; if (cum >= want) break; }
            if (cum < want) cum += hist[0][0];        // d==0 fallthrough
            shWant = want - (cum - hist[0][d]);
            shPrefix = (prefix << 8) | (uint)d;
        }
        __syncthreads();
        prefix = shPrefix; want = shWant;
        __syncthreads();
    }
    uint T = prefix, needEq = want;
    uint runningEq = 0;
    for (int base = 0; base < N0; base += 256) {
        int i = base + tid;
        uint k = (i < N0) ? keyOf(sc[i]) : 0u;
        bool isEq = (i < N0) && (k == T);
        unsigned long long mask = __ballot(isEq);
        uint wprefix = (uint)__popcll(mask & ((1ull << lane) - 1ull));
        uint wcount = (uint)__popcll(mask);
        if (lane == 0) wtot[wave] = wcount;
        __syncthreads();
        uint before = 0;
#pragma unroll
        for (int w = 0; w < 4; w++) if (w < wave) before += wtot[w];
        uint total = wtot[0] + wtot[1] + wtot[2] + wtot[3];
        if (i < N0) {
            uchar s = 0;
            if (k > T) s = 1;
            else if (isEq && (runningEq + before + wprefix) < needEq) s = 1;
            sl[i] = s;
        }
        runningEq += total;
        __syncthreads();
    }
}

// ---------- conv2 (graph 0, selection-filtered) ----------
// dinv2[d] = sel[d] ? rsqrt(1 + #selected in-edges) : 0   (0 acts as edge mask)
__global__ void k_gdinv2(const int* rowptr, const int* csr, const uchar* sel,
                         float* dinv2) {
    int d = blockIdx.x * blockDim.x + threadIdx.x;
    if (d >= N0) return;
    float r = 0.f;
    if (sel[d]) {
        int c = 0;
        int beg = rowptr[d], end = rowptr[d + 1];
        for (int e = beg; e < end; e++) c += sel[csr[e]];
        r = rsqrtf(1.f + (float)c);
    }
    dinv2[d] = r;
}

__global__ void k_xw2(const float* h1, const float* score, const uchar* sel,
                      const float* W2, float* xw2) {
    int gt = blockIdx.x * blockDim.x + threadIdx.x;
    int i = gt >> 5, c = gt & 31;
    if (i >= N0) return;
    if (!sel[i]) return;
    float t = tanhf(score[i]);
    const float* row = h1 + (size_t)i * H1C;
    float acc = 0.f;
#pragma unroll
    for (int h = 0; h < H1C; h++) acc += row[h] * W2[h * H2C + c];
    xw2[i * H2C + c] = acc * t;
}

__global__ void k_gath2(const int* rowptr, const int* csr, const uchar* sel,
                        const float* dinv2, const float* xw2, float* acc2) {
    int wid = (blockIdx.x * blockDim.x + threadIdx.x) >> 6;
    int lane = threadIdx.x & 63;
    if (wid >= N0) return;
    int d = wid;
    if (!sel[d]) return;
    int c = lane & 31;
    int beg = rowptr[d], end = rowptr[d + 1];
    float a0 = 0.f, a1 = 0.f;
    int e = beg + (lane >> 5);
    for (; e + 2 < end; e += 4) {   // this half-wave handles e, e+2
        int s0 = csr[e], s1 = csr[e + 2];
        a0 += xw2[(size_t)s0 * H2C + c] * dinv2[s0];
        a1 += xw2[(size_t)s1 * H2C + c] * dinv2[s1];
    }
    if (e < end) {
        int s = csr[e];
        a0 += xw2[(size_t)s * H2C + c] * dinv2[s];
    }
    float acc = a0 + a1;
    acc += __shfl_xor(acc, 32, 64);
    if (lane < 32) acc2[(size_t)d * H2C + c] = acc * dinv2[d];
}

__global__ void k_fin2(const float* acc2, const float* xw2, const float* dinv2,
                       const uchar* sel, const float* b2, float* gmax) {
    __shared__ float m[32];
    int tid = threadIdx.x;
    if (tid < 32) m[tid] = 0.f;
    __syncthreads();
    int i = blockIdx.x * 8 + (tid >> 5);
    int c = tid & 31;
    float v = 0.f;
    if (i < N0 && sel[i]) {
        float di = dinv2[i];
        v = fmaxf(acc2[(size_t)i * H2C + c] + xw2[(size_t)i * H2C + c] * di * di + b2[c], 0.f);
    }
    atomicMax((int*)&m[c], __float_as_int(v));
    __syncthreads();
    if (tid < 32) atomicMax((int*)&gmax[tid], __float_as_int(m[tid]));
}

// ---------- graphs 1..63: h2 + max pool ----------
// 68 blocks per graph (4 waves each = 272 waves >= ceil(17186/64)=269).
// CHUNKED recompute: per 16-channel chunk re-run the h-loop from the 6 cached
// inputs. Peak live state ~30 VGPR (acc[16]+xr[6]+temps) -- fits the ~56-VGPR
// allocation the compiler picks, so no scratch spill (R3/R4: 93MB WRITE_SIZE
// of spill leakage at acc[32]). Outer chunk loop is unroll-1 so the two
// acc[16] lifetimes never overlap.
#define BPGR 68
#define CCH 16
__global__ void k_rest_pool(const float* __restrict__ x, const float* __restrict__ score,
                            const uchar* __restrict__ sel,
                            const float* __restrict__ W1, const float* __restrict__ b1,
                            const float* __restrict__ W2, const float* __restrict__ b2,
                            float* gmax) {
    __shared__ float m[H2C];
    int tid = threadIdx.x;
    if (tid < H2C) m[tid] = 0.f;
    __syncthreads();
    int lane = tid & 63;
    int g = blockIdx.x / BPGR + 1;
    int wslot = (blockIdx.x % BPGR) * 4 + (tid >> 6);
    int li = wslot * 64 + lane;
    bool inb = li < N0;
    int n = inb ? (g * N0 + li) : 0;
    bool valid = inb && sel[n];
    float xr[FIN] = {0.f, 0.f, 0.f, 0.f, 0.f, 0.f};
    if (valid) {
        const float* xp = x + (size_t)n * FIN;
#pragma unroll
        for (int f = 0; f < FIN; f++) xr[f] = xp[f];
    }
    float t = valid ? tanhf(score[n]) : 0.f;
#pragma unroll 1
    for (int cc = 0; cc < H2C; cc += CCH) {
        float acc[CCH];
#pragma unroll
        for (int j = 0; j < CCH; j++) acc[j] = 0.f;
#pragma unroll
        for (int h = 0; h < H1C; h++) {
            float a = b1[h];
#pragma unroll
            for (int f = 0; f < FIN; f++) a += xr[f] * W1[f * H1C + h];
            float hv = fmaxf(a, 0.f);
#pragma unroll
            for (int j = 0; j < CCH; j++) acc[j] += hv * W2[h * H2C + cc + j];
        }
#pragma unroll
        for (int j = 0; j < CCH; j++) {
            float v = valid ? fmaxf(t * acc[j] + b2[cc + j], 0.f) : 0.f;
#pragma unroll
            for (int o = 32; o > 0; o >>= 1) v = fmaxf(v, __shfl_xor(v, o, 64));
            if (lane == 0) atomicMax((int*)&m[cc + j], __float_as_int(v));
        }
    }
    __syncthreads();
    if (tid < H2C) atomicMax((int*)&gmax[g * H2C + tid], __float_as_int(m[tid]));
}

// ---------- readout ----------
__global__ void k_final(const float* gmax, const float* Wf, const float* bf, float* out) {
    int g = threadIdx.x;
    if (g < BATCH) {
        float acc = bf[0];
        for (int c = 0; c < H2C; c++) acc += gmax[g * H2C + c] * Wf[c];
        out[g] = 1.f / (1.f + expf(-acc));
    }
}

extern "C" void kernel_launch(void* const* d_in, const int* in_sizes, int n_in,
                              void* d_out, int out_size, void* d_ws, size_t ws_size,
                              hipStream_t stream) {
    const float* data = (const float*)d_in[0];
    const void*  ei   = d_in[1];
    const float* W1   = (const float*)d_in[2];
    const float* b1   = (const float*)d_in[3];
    const float* Wp   = (const float*)d_in[4];
    const float* bp   = (const float*)d_in[5];
    const float* W2   = (const float*)d_in[6];
    const float* b2   = (const float*)d_in[7];
    const float* Wf   = (const float*)d_in[8];
    const float* bf   = (const float*)d_in[9];
    float* out = (float*)d_out;

    char* ws = (char*)d_ws;
    size_t off = 0;
    auto A = [&](size_t bytes) -> size_t {
        size_t o = off; off += (bytes + 511) & ~(size_t)511; return o;
    };
    // zero-initialized region (single memset)
    size_t o_deg0 = A((size_t)N0 * 4);
    size_t o_cnt  = A((size_t)N0 * 4);
    size_t o_gmax = A((size_t)BATCH * H2C * 4);
    size_t zbytes = off;
    // rest
    size_t o_src  = A((size_t)NE * 4);
    size_t o_dst  = A((size_t)NE * 4);
    size_t o_rp   = A((size_t)(N0 + 1) * 4);
    size_t o_csr  = A((size_t)NE * 4);
    size_t o_xw1  = A((size_t)N0 * H1C * 4);
    size_t o_h1   = A((size_t)N0 * H1C * 4);
    size_t o_di0  = A((size_t)N0 * 4);
    size_t o_di2  = A((size_t)N0 * 4);
    size_t o_h1w  = A((size_t)N0 * 4);
    size_t o_scr  = A((size_t)NT * 4);
    size_t o_sel  = A((size_t)NT);
    size_t o_xw2  = A((size_t)N0 * H2C * 4);
    size_t o_acc2 = A((size_t)N0 * H2C * 4);
    size_t o_flag = A(4);

    uint*  deg0 = (uint*)(ws + o_deg0);
    uint*  cnt  = (uint*)(ws + o_cnt);
    float* gmax = (float*)(ws + o_gmax);
    int*   src  = (int*)(ws + o_src);
    int*   dst  = (int*)(ws + o_dst);
    int*   rp   = (int*)(ws + o_rp);
    int*   csr  = (int*)(ws + o_csr);
    float* xw1  = (float*)(ws + o_xw1);
    float* h1   = (float*)(ws + o_h1);
    float* di0  = (float*)(ws + o_di0);
    float* di2  = (float*)(ws + o_di2);
    float* h1w  = (float*)(ws + o_h1w);
    float* scr  = (float*)(ws + o_scr);
    uchar* sel  = (uchar*)(ws + o_sel);
    float* xw2  = (float*)(ws + o_xw2);
    float* acc2 = (float*)(ws + o_acc2);
    int*   flag = (int*)(ws + o_flag);

    hipMemsetAsync(ws, 0, zbytes, stream);

    k_detect<<<1, 256, 0, stream>>>((const uint*)ei, flag);
    k_convert<<<2048, 256, 0, stream>>>(ei, flag, src, dst);
    k_deg<<<(NE + 255) / 256, 256, 0, stream>>>(dst, deg0);
    k_scan<<<1, 256, 0, stream>>>(deg0, rp);
    k_scatter<<<(NE + 255) / 256, 256, 0, stream>>>(src, dst, rp, cnt, csr);
    k_xw1<<<(N0 * H1C + 255) / 256, 256, 0, stream>>>(data, W1, xw1);
    k_dinv<<<(N0 + 255) / 256, 256, 0, stream>>>(deg0, di0);
    k_gath1<<<(N0 * 64 + 255) / 256, 256, 0, stream>>>(rp, csr, di0, xw1, b1, h1);
    k_h1w<<<(N0 + 255) / 256, 256, 0, stream>>>(h1, Wp, h1w);
    k_gscore0<<<(N0 + 255) / 256, 256, 0, stream>>>(rp, csr, di0, h1w, bp, scr);
    k_score_rest<<<(NT - N0 + 255) / 256, 256, 0, stream>>>(data, W1, b1, Wp, bp, scr);
    k_topk<<<BATCH, 256, 0, stream>>>(scr, sel);
    k_gdinv2<<<(N0 + 255) / 256, 256, 0, stream>>>(rp, csr, sel, di2);
    k_xw2<<<(N0 * H2C + 255) / 256, 256, 0, stream>>>(h1, scr, sel, W2, xw2);
    k_gath2<<<(N0 * 64 + 255) / 256, 256, 0, stream>>>(rp, csr, sel, di2, xw2, acc2);
    k_fin2<<<(N0 + 7) / 8, 256, 0, stream>>>(acc2, xw2, di2, sel, b2, gmax);
    k_rest_pool<<<(BATCH - 1) * BPGR, 256, 0, stream>>>(data, scr, sel, W1, b1, W2, b2, gmax);
    k_final<<<1, 64, 0, stream>>>(gmax, Wf, bf, out);
}